// Round 17
// baseline (157.906 us; speedup 1.0000x reference)
//
#include <hip/hip_runtime.h>
#include <hip/hip_bf16.h>

// NA Spatial MSA, fused:  out = attn @ (xw @ (Wv@Wo)) + bo
// R17: ring-3 deep pipeline, all-DMA staging, manual per-wave counted vmcnt.
//  - 256 blocks (1/CU) x 16 windows, 512 thr. LDS 128KB: x ring 3x32KB
//    (f32 K-halves, pre-swizzled DMA) + attn 2x16KB (f32, DMA, cvt at read).
//  - ZERO tracked global loads in the loop (WT hoisted, attn DMA'd) ->
//    vmcnt FIFO is fully manual. Per wave per phase: A issues {4 xDMA,
//    2 attnDMA}; B issues {4 xDMA, 32 stores}.
//  - Counted waits (never 0): A-end vmcnt(38) retires exactly x(w,h1);
//    B-end vmcnt(36) retires x(w+1,h0)+attn(w+1). Newest stage group and
//    stores ALWAYS ride -> ~96KB/CU continuously in flight (R16 drained to
//    0 every window -> demand duty ~30% -> 2.7 TB/s cap).
//  - Occupancy stays 1 blk/CU by design (R16 decode: AGPRs uncounted in
//    VGPR_Count -> 2 waves/SIMD true -> second block never fit).

typedef __bf16 bf16x8 __attribute__((ext_vector_type(8)));
typedef float  f32x16 __attribute__((ext_vector_type(16)));
typedef float  f32x4  __attribute__((ext_vector_type(4)));
typedef unsigned int uint;
typedef uint   uint4v __attribute__((ext_vector_type(4)));

#define MFMA32(a, b, c) __builtin_amdgcn_mfma_f32_32x32x16_bf16(a, b, c, 0, 0, 0)

// ---------------- Stage 0: WT = (Wv @ Wo)^T in bf16 ----------------
__global__ void wfuse_kernel(const float* __restrict__ Wv,
                             const float* __restrict__ Wo,
                             __bf16* __restrict__ WT) {
  const int n = blockIdx.x;
  const int k = threadIdx.x;
  const float* wvrow = Wv + k * 256;
  float acc = 0.f;
#pragma unroll 4
  for (int j = 0; j < 256; j += 4) {
    f32x4 wv = *(const f32x4*)(wvrow + j);
    acc += wv.x * Wo[(j + 0) * 256 + n];
    acc += wv.y * Wo[(j + 1) * 256 + n];
    acc += wv.z * Wo[(j + 2) * 256 + n];
    acc += wv.w * Wo[(j + 3) * 256 + n];
  }
  WT[n * 256 + k] = (__bf16)acc;
}

static __device__ __forceinline__ uint pkbf(float lo, float hi) {
  return (uint)__builtin_bit_cast(unsigned short, (__bf16)lo) |
         ((uint)__builtin_bit_cast(unsigned short, (__bf16)hi) << 16);
}

static __device__ __forceinline__ bf16x8 cvt8(f32x4 u, f32x4 v) {
  bf16x8 r;
  r[0] = (__bf16)u.x; r[1] = (__bf16)u.y; r[2] = (__bf16)u.z; r[3] = (__bf16)u.w;
  r[4] = (__bf16)v.x; r[5] = (__bf16)v.y; r[6] = (__bf16)v.z; r[7] = (__bf16)v.w;
  return r;
}

// GEMM2 B-frags from GEMM1 acc via pack + shfl_xor(32). (verified R3..R16)
static __device__ __forceinline__ void build_bfrags(const f32x16 acc, int lh,
                                                    bf16x8* bf) {
  uint wd0 = pkbf(acc[0],  acc[1]);
  uint wd1 = pkbf(acc[2],  acc[3]);
  uint wd2 = pkbf(acc[4],  acc[5]);
  uint wd3 = pkbf(acc[6],  acc[7]);
  uint wd4 = pkbf(acc[8],  acc[9]);
  uint wd5 = pkbf(acc[10], acc[11]);
  uint wd6 = pkbf(acc[12], acc[13]);
  uint wd7 = pkbf(acc[14], acc[15]);
  {
    uint o0 = (uint)__shfl_xor((int)wd2, 32);
    uint o1 = (uint)__shfl_xor((int)wd3, 32);
    uint o2 = (uint)__shfl_xor((int)wd0, 32);
    uint o3 = (uint)__shfl_xor((int)wd1, 32);
    uint4v uv = { lh ? o0 : wd0, lh ? o1 : wd1,
                  lh ? wd2 : o2, lh ? wd3 : o3 };
    bf[0] = __builtin_bit_cast(bf16x8, uv);
  }
  {
    uint o0 = (uint)__shfl_xor((int)wd6, 32);
    uint o1 = (uint)__shfl_xor((int)wd7, 32);
    uint o2 = (uint)__shfl_xor((int)wd4, 32);
    uint o3 = (uint)__shfl_xor((int)wd5, 32);
    uint4v uv = { lh ? o0 : wd4, lh ? o1 : wd5,
                  lh ? wd6 : o2, lh ? wd7 : o3 };
    bf[1] = __builtin_bit_cast(bf16x8, uv);
  }
}

static __device__ __forceinline__ long wbase(int w) {
  int wi = w & 31;
  int hi = (w >> 5) & 31;
  int b  = w >> 10;
  return (((long)(b * 256 + hi * 8)) * 256 + wi * 8) * 256;
}

// async 16B/lane global->LDS DMA (LDS dest = wave-uniform base + lane*16)
static __device__ __forceinline__ void dma16(const float* gp, char* lp) {
  __builtin_amdgcn_global_load_lds(
      (const __attribute__((address_space(1))) uint*)gp,
      (__attribute__((address_space(3))) uint*)lp, 16, 0, 0);
}

// read bf16x8 A-frag from half-K f32 x strip: tok row = 512B, granule g
// (16B, 0..31) lives at slot g ^ (tok&31).  (R10/R16-verified layout)
static __device__ __forceinline__ bf16x8 ldax_h(const char* xs, int tok, int g) {
  const int sw = tok & 31;
  f32x4 u = *(const f32x4*)(xs + tok * 512 + ((g ^ sw) << 4));
  f32x4 v = *(const f32x4*)(xs + tok * 512 + (((g + 1) ^ sw) << 4));
  return cvt8(u, v);
}

// read bf16x8 A-frag from f32 attn buf: row = 256B (16 granules),
// granule g lives at slot g ^ (row&15).
static __device__ __forceinline__ bf16x8 ldat(const char* as, int row, int g) {
  const int sw = row & 15;
  f32x4 u = *(const f32x4*)(as + row * 256 + ((g ^ sw) << 4));
  f32x4 v = *(const f32x4*)(as + row * 256 + (((g + 1) ^ sw) << 4));
  return cvt8(u, v);
}

// ---------------- Main kernel ----------------
// LDS 128KB: x ring buffers at 0/32768/65536 (32KB f32 K-halves);
// attn f32 at 98304 + sel*16384 (16KB each).
__global__ __launch_bounds__(512, 2)
void na_msa_kernel(const float* __restrict__ x,
                   const float* __restrict__ attn,
                   const __bf16* __restrict__ WT,
                   const float* __restrict__ bo,
                   float* __restrict__ out) {
  __shared__ char lds[131072];

  const int t    = threadIdx.x;
  const int lane = t & 63;
  const int wvi  = t >> 6;              // wave 0..7, owns ch [32wvi, 32wvi+32)
  const int ln31 = lane & 31;
  const int lh   = lane >> 5;

  const __bf16* wtp = WT + (wvi * 32 + ln31) * 256 + 8 * lh;
  const float bv = bo[wvi * 32 + ln31];

  const int w0 = blockIdx.x * 16;

  // x K-half staging: 32 DMAs (4/wave). DMA tp covers tok pair {2tp,2tp+1}
  // (lane>>5 selects); source granule perm = (lane&31)^(tok&31) pre-swizzles
  // so the linear LDS dest yields the tile ldax_h expects.   [per-wave: 4 ops]
#define STAGE_XH(W, HALF, BUFOFF) do {                                     \
    const float* xp_ = x + wbase(W);                                       \
    _Pragma("unroll")                                                      \
    for (int jj = 0; jj < 4; ++jj) {                                       \
      int tp_ = jj * 8 + wvi;                                              \
      int tok_ = tp_ * 2 + (lane >> 5);                                    \
      int perm_ = (lane & 31) ^ (tok_ & 31);                               \
      const float* gp_ = xp_ + (tok_ >> 3) * 65536 + (tok_ & 7) * 256 +    \
                         (HALF) * 128 + perm_ * 4;                         \
      int off_ = __builtin_amdgcn_readfirstlane((BUFOFF) + tp_ * 1024);    \
      dma16(gp_, lds + off_);                                              \
    } } while (0)

  // attn f32 staging: 16 DMAs (2/wave). DMA j covers rows 4j..4j+3 (1KB);
  // lane l -> row 4j + (l>>4), slot l&15 holding granule (l&15)^(row&15).
  // [per-wave: 2 ops]
#define STAGE_AT(W, BUFOFF) do {                                           \
    const float* ap_ = attn + (long)(W) * 4096;                            \
    _Pragma("unroll")                                                      \
    for (int jj = 0; jj < 2; ++jj) {                                       \
      int j_ = wvi * 2 + jj;                                               \
      int row_ = j_ * 4 + (lane >> 4);                                     \
      int g_ = (lane & 15) ^ (row_ & 15);                                  \
      const float* gp_ = ap_ + row_ * 64 + g_ * 4;                         \
      int off_ = __builtin_amdgcn_readfirstlane((BUFOFF) + j_ * 1024);     \
      dma16(gp_, lds + off_);                                              \
    } } while (0)

  // ---- prologue: hoist the 16 loop-invariant WT b0 frags into VGPRs ----
  bf16x8 wb[16];
#pragma unroll
  for (int ks = 0; ks < 16; ++ks) wb[ks] = *(const bf16x8*)(wtp + ks * 16);

  // ---- prologue: stage (w0,h0), attn(w0), (w0,h1); full drain once ----
  STAGE_XH(w0, 0, 0);
  STAGE_AT(w0, 98304);
  STAGE_XH(w0, 1, 32768);
  asm volatile("s_waitcnt vmcnt(0) lgkmcnt(0)" ::: "memory");
  __builtin_amdgcn_s_barrier();
  __builtin_amdgcn_sched_barrier(0);

  int rA = 0, rB = 32768, rC = 65536;   // ring: rA=(w,h0) rB=(w,h1) rC=free

#pragma unroll 1
  for (int i = 0; i < 16; ++i) {
    const int w = w0 + i;
    const char* xsA = lds + rA;
    const char* xsB = lds + rB;
    const char* as  = lds + 98304 + (i & 1) * 16384;

    // ======== PHASE A: issue {x(w+1,h0)->rC, attn(w+1)}; GEMM1 ks 0..7 ====
    if (i < 15) {
      STAGE_XH(w + 1, 0, rC);
      STAGE_AT(w + 1, 98304 + ((i + 1) & 1) * 16384);
    }
    __builtin_amdgcn_sched_barrier(0);

    f32x16 acc0 = {}, acc1 = {};
#pragma unroll
    for (int ks = 0; ks < 8; ++ks) {
      int g = 4 * ks + 2 * lh;
      bf16x8 a0 = ldax_h(xsA, ln31, g);            // toks 0..31
      bf16x8 a1 = ldax_h(xsA, 32 + ln31, g);       // toks 32..63
      acc0 = MFMA32(a0, wb[ks], acc0);
      acc1 = MFMA32(a1, wb[ks], acc1);
    }
    // A-end: retire exactly x(w,h1) [oldest 4]; newer 38 = stores(w-1)32 +
    // x(w+1,h0)4 + attn(w+1)2 keep riding. Tail i=15: no new issues ->
    // carry = x(w,h1)4 + stores(w-1)32 -> vmcnt(32).
    if (i < 15) {
      asm volatile("s_waitcnt vmcnt(38) lgkmcnt(0)" ::: "memory");
    } else {
      asm volatile("s_waitcnt vmcnt(32) lgkmcnt(0)" ::: "memory");
    }
    __builtin_amdgcn_s_barrier();
    __builtin_amdgcn_sched_barrier(0);

    // ======== PHASE B: issue x(w+1,h1)->rA; GEMM1 ks 8..15; GEMM2; store ==
    if (i < 15) STAGE_XH(w + 1, 1, rA);   // rA readers finished at A barrier
    __builtin_amdgcn_sched_barrier(0);

#pragma unroll
    for (int ks = 8; ks < 16; ++ks) {
      int g = 4 * (ks - 8) + 2 * lh;
      bf16x8 a0 = ldax_h(xsB, ln31, g);
      bf16x8 a1 = ldax_h(xsB, 32 + ln31, g);
      acc0 = MFMA32(a0, wb[ks], acc0);
      acc1 = MFMA32(a1, wb[ks], acc1);
    }

    bf16x8 bfr[4];
    build_bfrags(acc0, lh, &bfr[0]);
    build_bfrags(acc1, lh, &bfr[2]);

    float* op = out + wbase(w);
    const int ch = wvi * 32 + ln31;

    // GEMM2 split (o0 -> store -> o1 -> store) caps register pressure.
    {
      f32x16 o0 = {};
#pragma unroll
      for (int ks = 0; ks < 4; ++ks) {
        int g = 4 * ks + 2 * lh;
        o0 = MFMA32(ldat(as, ln31, g), bfr[ks], o0);
      }
#pragma unroll
      for (int r = 0; r < 16; ++r) {
        int tok = (r & 3) + 8 * (r >> 2) + 4 * lh;
        op[(tok >> 3) * 65536 + (tok & 7) * 256 + ch] = o0[r] + bv;
      }
    }
    {
      f32x16 o1 = {};
#pragma unroll
      for (int ks = 0; ks < 4; ++ks) {
        int g = 4 * ks + 2 * lh;
        o1 = MFMA32(ldat(as, 32 + ln31, g), bfr[ks], o1);
      }
#pragma unroll
      for (int r = 0; r < 16; ++r) {
        int tok = 32 + (r & 3) + 8 * (r >> 2) + 4 * lh;
        op[(tok >> 3) * 65536 + (tok & 7) * 256 + ch] = o1[r] + bv;
      }
    }

    // B-end: retire stores(w-1) remnant + x(w+1,h0) + attn(w+1); newer 36 =
    // x(w+1,h1)4 + stores(w)32 keep riding. Final iter: no wait (kernel end).
    if (i < 15) {
      asm volatile("s_waitcnt vmcnt(36) lgkmcnt(0)" ::: "memory");
      __builtin_amdgcn_s_barrier();
      __builtin_amdgcn_sched_barrier(0);
    }

    // rotate ring: new (w+1,h0) is in rC, new (w+1,h1) in old rA.
    int tmp = rC; rC = rB; rB = rA; rA = tmp;
  }
#undef STAGE_XH
#undef STAGE_AT
}

extern "C" void kernel_launch(void* const* d_in, const int* in_sizes, int n_in,
                              void* d_out, int out_size, void* d_ws, size_t ws_size,
                              hipStream_t stream) {
  const float* x    = (const float*)d_in[0];
  const float* attn = (const float*)d_in[1];
  const float* Wv   = (const float*)d_in[2];
  const float* Wo   = (const float*)d_in[3];
  const float* bo   = (const float*)d_in[4];
  float* out = (float*)d_out;
  __bf16* WT = (__bf16*)d_ws;   // 256*256*2 = 128 KB scratch

  wfuse_kernel<<<256, 256, 0, stream>>>(Wv, Wo, WT);
  na_msa_kernel<<<256, 512, 0, stream>>>(x, attn, WT, bo, out);
}

// Round 18
// 153.224 us; speedup vs baseline: 1.0306x; 1.0306x over previous
//
#include <hip/hip_runtime.h>
#include <hip/hip_bf16.h>

// NA Spatial MSA, fused:  out = attn @ (xw @ (Wv@Wo)) + bo
// R18: bf16-in-LDS via reg-staging (R3/R6 design, spill fixed by (512,2)).
// R17 decode: dur/window = HBM(5.9us) + LDS/cvt(3.5us) SUMMED. The f32-LDS
// design re-reads 64KB x 8 waves (512KB LDS/window) with 8 cvts per frag
// (256 v_cvt/thread in GEMM1). bf16 staging: cvt ONCE at stage (32/thread),
// GEMM1 A-frag = single ds_read_b128 -> LDS reads halve, GEMM1 cvt -> 0.
// vmcnt discipline (R13): loads at loop-top (oldest), cvt+ds_write after
// stores (compiler wait = counted, 32 stores ride), barrier = lgkmcnt only.
// NO vmcnt drain anywhere -> stores ride to kernel end.

typedef __bf16 bf16x8 __attribute__((ext_vector_type(8)));
typedef __bf16 bf16x4 __attribute__((ext_vector_type(4)));
typedef float  f32x16 __attribute__((ext_vector_type(16)));
typedef float  f32x4  __attribute__((ext_vector_type(4)));
typedef unsigned int uint;
typedef uint   uint4v __attribute__((ext_vector_type(4)));

#define MFMA32(a, b, c) __builtin_amdgcn_mfma_f32_32x32x16_bf16(a, b, c, 0, 0, 0)

// ---------------- Stage 0: WT = (Wv @ Wo)^T in bf16 ----------------
__global__ void wfuse_kernel(const float* __restrict__ Wv,
                             const float* __restrict__ Wo,
                             __bf16* __restrict__ WT) {
  const int n = blockIdx.x;
  const int k = threadIdx.x;
  const float* wvrow = Wv + k * 256;
  float acc = 0.f;
#pragma unroll 4
  for (int j = 0; j < 256; j += 4) {
    f32x4 wv = *(const f32x4*)(wvrow + j);
    acc += wv.x * Wo[(j + 0) * 256 + n];
    acc += wv.y * Wo[(j + 1) * 256 + n];
    acc += wv.z * Wo[(j + 2) * 256 + n];
    acc += wv.w * Wo[(j + 3) * 256 + n];
  }
  WT[n * 256 + k] = (__bf16)acc;
}

static __device__ __forceinline__ uint pkbf(float lo, float hi) {
  return (uint)__builtin_bit_cast(unsigned short, (__bf16)lo) |
         ((uint)__builtin_bit_cast(unsigned short, (__bf16)hi) << 16);
}

// GEMM2 B-frags from GEMM1 acc via pack + shfl_xor(32). (verified R3..R17)
static __device__ __forceinline__ void build_bfrags(const f32x16 acc, int lh,
                                                    bf16x8* bf) {
  uint wd0 = pkbf(acc[0],  acc[1]);
  uint wd1 = pkbf(acc[2],  acc[3]);
  uint wd2 = pkbf(acc[4],  acc[5]);
  uint wd3 = pkbf(acc[6],  acc[7]);
  uint wd4 = pkbf(acc[8],  acc[9]);
  uint wd5 = pkbf(acc[10], acc[11]);
  uint wd6 = pkbf(acc[12], acc[13]);
  uint wd7 = pkbf(acc[14], acc[15]);
  {
    uint o0 = (uint)__shfl_xor((int)wd2, 32);
    uint o1 = (uint)__shfl_xor((int)wd3, 32);
    uint o2 = (uint)__shfl_xor((int)wd0, 32);
    uint o3 = (uint)__shfl_xor((int)wd1, 32);
    uint4v uv = { lh ? o0 : wd0, lh ? o1 : wd1,
                  lh ? wd2 : o2, lh ? wd3 : o3 };
    bf[0] = __builtin_bit_cast(bf16x8, uv);
  }
  {
    uint o0 = (uint)__shfl_xor((int)wd6, 32);
    uint o1 = (uint)__shfl_xor((int)wd7, 32);
    uint o2 = (uint)__shfl_xor((int)wd4, 32);
    uint o3 = (uint)__shfl_xor((int)wd5, 32);
    uint4v uv = { lh ? o0 : wd4, lh ? o1 : wd5,
                  lh ? wd6 : o2, lh ? wd7 : o3 };
    bf[1] = __builtin_bit_cast(bf16x8, uv);
  }
}

static __device__ __forceinline__ long wbase(int w) {
  int wi = w & 31;
  int hi = (w >> 5) & 31;
  int b  = w >> 10;
  return (((long)(b * 256 + hi * 8)) * 256 + wi * 8) * 256;
}

// ---------------- Main kernel ----------------
// LDS 80KB: 2 buffers x (32KB x-bf16 swizzled + 8KB attn bf16 swizzled).
__global__ __launch_bounds__(512, 2)
void na_msa_kernel(const float* __restrict__ x,
                   const float* __restrict__ attn,
                   const __bf16* __restrict__ WT,
                   const float* __restrict__ bo,
                   float* __restrict__ out) {
  __shared__ char lds[81920];

  const int t    = threadIdx.x;
  const int lane = t & 63;
  const int wvi  = t >> 6;              // wave 0..7, owns ch [32wvi, 32wvi+32)
  const int ln31 = lane & 31;
  const int lh   = lane >> 5;

  const __bf16* wtp = WT + (wvi * 32 + ln31) * 256 + 8 * lh;
  const float bv = bo[wvi * 32 + ln31];

  // x staging geometry (R5/R6-verified): chunk J = h-row J; thread t loads
  // f32x4 at xp + J*65536 + t*4 -> tok = J*8 + (t>>6), ch0 = (t&63)*4.
  const int tq   = t >> 6;
  const int xch0 = (t & 63) * 4;
  // attn staging geometry: thread t handles f32x4 idx {t, 512+t}
  const int arow0 = t >> 4;
  const int ak0   = (t & 15) * 4;

  const int w0 = blockIdx.x * 16;

#define XBYT(J)  ((((J) * 8 + tq) * 512) + ((xch0 * 2) ^ ((((J) * 8 + tq) & 31) << 4)))
#define CVT4(V)  bf16x4{ (__bf16)(V).x, (__bf16)(V).y, (__bf16)(V).z, (__bf16)(V).w }

#define AWR(BAT, R0, R1) do {                                              \
    *(bf16x4*)((BAT) + arow0 * 128 + ((ak0 * 2) ^ ((arow0 & 7) << 4))) =   \
        bf16x4{ (__bf16)(R0).x, (__bf16)(R0).y, (__bf16)(R0).z, (__bf16)(R0).w }; \
    int row1_ = 32 + arow0;                                                \
    *(bf16x4*)((BAT) + row1_ * 128 + ((ak0 * 2) ^ ((row1_ & 7) << 4))) =   \
        bf16x4{ (__bf16)(R1).x, (__bf16)(R1).y, (__bf16)(R1).z, (__bf16)(R1).w }; \
    } while (0)

  // ---- prologue: hoist the 16 loop-invariant WT b0 frags into VGPRs ----
  bf16x8 wb[16];
#pragma unroll
  for (int ks = 0; ks < 16; ++ks) wb[ks] = *(const bf16x8*)(wtp + ks * 16);

  // ---- prologue: stage window w0 into buffer 0 (load->cvt->ds_write) ----
  {
    const float* xp = x + wbase(w0);
    const float* ap = attn + (long)w0 * 4096;
    f32x4 v0 = *(const f32x4*)(xp + 0 * 65536 + t * 4);
    f32x4 v1 = *(const f32x4*)(xp + 1 * 65536 + t * 4);
    f32x4 v2 = *(const f32x4*)(xp + 2 * 65536 + t * 4);
    f32x4 v3 = *(const f32x4*)(xp + 3 * 65536 + t * 4);
    f32x4 v4 = *(const f32x4*)(xp + 4 * 65536 + t * 4);
    f32x4 v5 = *(const f32x4*)(xp + 5 * 65536 + t * 4);
    f32x4 v6 = *(const f32x4*)(xp + 6 * 65536 + t * 4);
    f32x4 v7 = *(const f32x4*)(xp + 7 * 65536 + t * 4);
    f32x4 a0 = *(const f32x4*)(ap + t * 4);
    f32x4 a1 = *(const f32x4*)(ap + (512 + t) * 4);
    *(bf16x4*)(lds + XBYT(0)) = CVT4(v0);
    *(bf16x4*)(lds + XBYT(1)) = CVT4(v1);
    *(bf16x4*)(lds + XBYT(2)) = CVT4(v2);
    *(bf16x4*)(lds + XBYT(3)) = CVT4(v3);
    *(bf16x4*)(lds + XBYT(4)) = CVT4(v4);
    *(bf16x4*)(lds + XBYT(5)) = CVT4(v5);
    *(bf16x4*)(lds + XBYT(6)) = CVT4(v6);
    *(bf16x4*)(lds + XBYT(7)) = CVT4(v7);
    AWR(lds + 32768, a0, a1);
  }
  asm volatile("s_waitcnt lgkmcnt(0)" ::: "memory");
  __builtin_amdgcn_s_barrier();
  __builtin_amdgcn_sched_barrier(0);

#pragma unroll 1
  for (int i = 0; i < 16; ++i) {
    const int w = w0 + i;
    const char* xs = lds + (i & 1) * 40960;
    const char* as = xs + 32768;

    // ---- loop-top: issue next window's 10 loads (oldest VMEM ops) ----
    f32x4 px0, px1, px2, px3, px4, px5, px6, px7, pa0, pa1;
    if (i < 15) {
      const float* xp = x + wbase(w + 1);
      const float* ap = attn + (long)(w + 1) * 4096;
      px0 = *(const f32x4*)(xp + 0 * 65536 + t * 4);
      px1 = *(const f32x4*)(xp + 1 * 65536 + t * 4);
      px2 = *(const f32x4*)(xp + 2 * 65536 + t * 4);
      px3 = *(const f32x4*)(xp + 3 * 65536 + t * 4);
      px4 = *(const f32x4*)(xp + 4 * 65536 + t * 4);
      px5 = *(const f32x4*)(xp + 5 * 65536 + t * 4);
      px6 = *(const f32x4*)(xp + 6 * 65536 + t * 4);
      px7 = *(const f32x4*)(xp + 7 * 65536 + t * 4);
      pa0 = *(const f32x4*)(ap + t * 4);
      pa1 = *(const f32x4*)(ap + (512 + t) * 4);
    }
    __builtin_amdgcn_sched_barrier(0);   // pin: loads issued before GEMM1

    // ---- GEMM1: z = xw @ W, K=256. ONE ds_read_b128 per frag, zero cvt ----
    f32x16 acc0 = {}, acc1 = {};
#pragma unroll
    for (int ks = 0; ks < 16; ++ks) {
      int kk = ks * 16 + 8 * lh;
      int byt0 = ln31 * 512 + ((kk * 2) ^ (ln31 << 4));
      bf16x8 a0 = *(const bf16x8*)(xs + byt0);            // toks 0..31
      bf16x8 a1 = *(const bf16x8*)(xs + byt0 + 16384);    // toks 32..63
      acc0 = MFMA32(a0, wb[ks], acc0);
      acc1 = MFMA32(a1, wb[ks], acc1);
    }

    // ---- GEMM2 B-frags in-register ----
    bf16x8 bfr[4];
    build_bfrags(acc0, lh, &bfr[0]);
    build_bfrags(acc1, lh, &bfr[2]);

    float* op = out + wbase(w);
    const int ch = wvi * 32 + ln31;

    // ---- GEMM2 + store, split o0/o1 to cap register pressure ----
    {
      f32x16 o0 = {};
#pragma unroll
      for (int ks = 0; ks < 4; ++ks) {
        int kk = ks * 16 + 8 * lh;
        int ab0 = ln31 * 128 + ((kk * 2) ^ ((ln31 & 7) << 4));
        bf16x8 a0 = *(const bf16x8*)(as + ab0);
        o0 = MFMA32(a0, bfr[ks], o0);
      }
#pragma unroll
      for (int r = 0; r < 16; ++r) {
        int tok = (r & 3) + 8 * (r >> 2) + 4 * lh;
        op[(tok >> 3) * 65536 + (tok & 7) * 256 + ch] = o0[r] + bv;
      }
    }
    {
      f32x16 o1 = {};
#pragma unroll
      for (int ks = 0; ks < 4; ++ks) {
        int kk = ks * 16 + 8 * lh;
        int ab0 = ln31 * 128 + ((kk * 2) ^ ((ln31 & 7) << 4));
        bf16x8 a1 = *(const bf16x8*)(as + ab0 + 4096);
        o1 = MFMA32(a1, bfr[ks], o1);
      }
#pragma unroll
      for (int r = 0; r < 16; ++r) {
        int tok = 32 + (r & 3) + 8 * (r >> 2) + 4 * lh;
        op[(tok >> 3) * 65536 + (tok & 7) * 256 + ch] = o1[r] + bv;
      }
    }

    // ---- staging write AFTER stores: compiler's wait for the (old) loads
    // is counted (32 newer stores ride). cvt once, ds_write bf16. ----
    if (i < 15) {
      char* bxw = lds + ((i + 1) & 1) * 40960;
      *(bf16x4*)(bxw + XBYT(0)) = CVT4(px0);
      *(bf16x4*)(bxw + XBYT(1)) = CVT4(px1);
      *(bf16x4*)(bxw + XBYT(2)) = CVT4(px2);
      *(bf16x4*)(bxw + XBYT(3)) = CVT4(px3);
      *(bf16x4*)(bxw + XBYT(4)) = CVT4(px4);
      *(bf16x4*)(bxw + XBYT(5)) = CVT4(px5);
      *(bf16x4*)(bxw + XBYT(6)) = CVT4(px6);
      *(bf16x4*)(bxw + XBYT(7)) = CVT4(px7);
      AWR(bxw + 32768, pa0, pa1);
    }

    // ---- barrier: only LDS visibility needed; stores ride to kernel end --
    asm volatile("s_waitcnt lgkmcnt(0)" ::: "memory");
    __builtin_amdgcn_s_barrier();
    __builtin_amdgcn_sched_barrier(0);
  }
#undef XBYT
#undef CVT4
#undef AWR
}

extern "C" void kernel_launch(void* const* d_in, const int* in_sizes, int n_in,
                              void* d_out, int out_size, void* d_ws, size_t ws_size,
                              hipStream_t stream) {
  const float* x    = (const float*)d_in[0];
  const float* attn = (const float*)d_in[1];
  const float* Wv   = (const float*)d_in[2];
  const float* Wo   = (const float*)d_in[3];
  const float* bo   = (const float*)d_in[4];
  float* out = (float*)d_out;
  __bf16* WT = (__bf16*)d_ws;   // 256*256*2 = 128 KB scratch

  wfuse_kernel<<<256, 256, 0, stream>>>(Wv, Wo, WT);
  na_msa_kernel<<<256, 512, 0, stream>>>(x, attn, WT, bo, out);
}

// Round 19
// 152.788 us; speedup vs baseline: 1.0335x; 1.0029x over previous
//
#include <hip/hip_runtime.h>
#include <hip/hip_bf16.h>

// NA Spatial MSA, fused:  out = attn @ (xw @ (Wv@Wo)) + bo
// R19 = R18 with LDS trimmed 80->72KB so TWO blocks truly co-reside:
//   x dbuf 2x32KB bf16 (unchanged) + attn SINGLE 8KB buffer (+1 cheap
//   mid-iter barrier between last attn read and attn(w+1) write).
// Grid 512 x 8 windows = exactly 2 blocks/CU. R16/R18 never co-scheduled
// (R18 grid=256 -> 1/CU by construction; R16 2x80KB = exact LDS pool, no
// pack) -> the ledger's key combo {vmcnt-clean pipeline x 2 blocks/CU} is
// untested until now. All R13/R18 discipline kept: WT hoist, loads at top
// (oldest), staging writes after stores (counted wait), lgkm-only barriers.

typedef __bf16 bf16x8 __attribute__((ext_vector_type(8)));
typedef __bf16 bf16x4 __attribute__((ext_vector_type(4)));
typedef float  f32x16 __attribute__((ext_vector_type(16)));
typedef float  f32x4  __attribute__((ext_vector_type(4)));
typedef unsigned int uint;
typedef uint   uint4v __attribute__((ext_vector_type(4)));

#define MFMA32(a, b, c) __builtin_amdgcn_mfma_f32_32x32x16_bf16(a, b, c, 0, 0, 0)

// ---------------- Stage 0: WT = (Wv @ Wo)^T in bf16 ----------------
__global__ void wfuse_kernel(const float* __restrict__ Wv,
                             const float* __restrict__ Wo,
                             __bf16* __restrict__ WT) {
  const int n = blockIdx.x;
  const int k = threadIdx.x;
  const float* wvrow = Wv + k * 256;
  float acc = 0.f;
#pragma unroll 4
  for (int j = 0; j < 256; j += 4) {
    f32x4 wv = *(const f32x4*)(wvrow + j);
    acc += wv.x * Wo[(j + 0) * 256 + n];
    acc += wv.y * Wo[(j + 1) * 256 + n];
    acc += wv.z * Wo[(j + 2) * 256 + n];
    acc += wv.w * Wo[(j + 3) * 256 + n];
  }
  WT[n * 256 + k] = (__bf16)acc;
}

static __device__ __forceinline__ uint pkbf(float lo, float hi) {
  return (uint)__builtin_bit_cast(unsigned short, (__bf16)lo) |
         ((uint)__builtin_bit_cast(unsigned short, (__bf16)hi) << 16);
}

// GEMM2 B-frags from GEMM1 acc via pack + shfl_xor(32). (verified R3..R18)
static __device__ __forceinline__ void build_bfrags(const f32x16 acc, int lh,
                                                    bf16x8* bf) {
  uint wd0 = pkbf(acc[0],  acc[1]);
  uint wd1 = pkbf(acc[2],  acc[3]);
  uint wd2 = pkbf(acc[4],  acc[5]);
  uint wd3 = pkbf(acc[6],  acc[7]);
  uint wd4 = pkbf(acc[8],  acc[9]);
  uint wd5 = pkbf(acc[10], acc[11]);
  uint wd6 = pkbf(acc[12], acc[13]);
  uint wd7 = pkbf(acc[14], acc[15]);
  {
    uint o0 = (uint)__shfl_xor((int)wd2, 32);
    uint o1 = (uint)__shfl_xor((int)wd3, 32);
    uint o2 = (uint)__shfl_xor((int)wd0, 32);
    uint o3 = (uint)__shfl_xor((int)wd1, 32);
    uint4v uv = { lh ? o0 : wd0, lh ? o1 : wd1,
                  lh ? wd2 : o2, lh ? wd3 : o3 };
    bf[0] = __builtin_bit_cast(bf16x8, uv);
  }
  {
    uint o0 = (uint)__shfl_xor((int)wd6, 32);
    uint o1 = (uint)__shfl_xor((int)wd7, 32);
    uint o2 = (uint)__shfl_xor((int)wd4, 32);
    uint o3 = (uint)__shfl_xor((int)wd5, 32);
    uint4v uv = { lh ? o0 : wd4, lh ? o1 : wd5,
                  lh ? wd6 : o2, lh ? wd7 : o3 };
    bf[1] = __builtin_bit_cast(bf16x8, uv);
  }
}

static __device__ __forceinline__ long wbase(int w) {
  int wi = w & 31;
  int hi = (w >> 5) & 31;
  int b  = w >> 10;
  return (((long)(b * 256 + hi * 8)) * 256 + wi * 8) * 256;
}

// ---------------- Main kernel ----------------
// LDS 72KB: x bf16 dbuf at 0 / 32768 (32KB, [64tok][256ch] swizzled);
// attn bf16 SINGLE buffer at 65536 (8KB).
__global__ __launch_bounds__(512, 2)
void na_msa_kernel(const float* __restrict__ x,
                   const float* __restrict__ attn,
                   const __bf16* __restrict__ WT,
                   const float* __restrict__ bo,
                   float* __restrict__ out) {
  __shared__ char lds[73728];
  char* lds_at = lds + 65536;

  const int t    = threadIdx.x;
  const int lane = t & 63;
  const int wvi  = t >> 6;              // wave 0..7, owns ch [32wvi, 32wvi+32)
  const int ln31 = lane & 31;
  const int lh   = lane >> 5;

  const __bf16* wtp = WT + (wvi * 32 + ln31) * 256 + 8 * lh;
  const float bv = bo[wvi * 32 + ln31];

  // x staging geometry (R5/R18-verified): chunk J = h-row J; thread t loads
  // f32x4 at xp + J*65536 + t*4 -> tok = J*8 + (t>>6), ch0 = (t&63)*4.
  const int tq   = t >> 6;
  const int xch0 = (t & 63) * 4;
  // attn staging geometry: thread t handles f32x4 idx {t, 512+t}
  const int arow0 = t >> 4;
  const int ak0   = (t & 15) * 4;

  const int w0 = blockIdx.x * 8;

#define XBYT(J)  ((((J) * 8 + tq) * 512) + ((xch0 * 2) ^ ((((J) * 8 + tq) & 31) << 4)))
#define CVT4(V)  bf16x4{ (__bf16)(V).x, (__bf16)(V).y, (__bf16)(V).z, (__bf16)(V).w }

#define AWR(R0, R1) do {                                                   \
    *(bf16x4*)(lds_at + arow0 * 128 + ((ak0 * 2) ^ ((arow0 & 7) << 4))) =  \
        bf16x4{ (__bf16)(R0).x, (__bf16)(R0).y, (__bf16)(R0).z, (__bf16)(R0).w }; \
    int row1_ = 32 + arow0;                                                \
    *(bf16x4*)(lds_at + row1_ * 128 + ((ak0 * 2) ^ ((row1_ & 7) << 4))) =  \
        bf16x4{ (__bf16)(R1).x, (__bf16)(R1).y, (__bf16)(R1).z, (__bf16)(R1).w }; \
    } while (0)

  // ---- prologue: hoist the 16 loop-invariant WT b0 frags into VGPRs ----
  bf16x8 wb[16];
#pragma unroll
  for (int ks = 0; ks < 16; ++ks) wb[ks] = *(const bf16x8*)(wtp + ks * 16);

  // ---- prologue: stage window w0 into buffer 0 (load->cvt->ds_write) ----
  {
    const float* xp = x + wbase(w0);
    const float* ap = attn + (long)w0 * 4096;
    f32x4 v0 = *(const f32x4*)(xp + 0 * 65536 + t * 4);
    f32x4 v1 = *(const f32x4*)(xp + 1 * 65536 + t * 4);
    f32x4 v2 = *(const f32x4*)(xp + 2 * 65536 + t * 4);
    f32x4 v3 = *(const f32x4*)(xp + 3 * 65536 + t * 4);
    f32x4 v4 = *(const f32x4*)(xp + 4 * 65536 + t * 4);
    f32x4 v5 = *(const f32x4*)(xp + 5 * 65536 + t * 4);
    f32x4 v6 = *(const f32x4*)(xp + 6 * 65536 + t * 4);
    f32x4 v7 = *(const f32x4*)(xp + 7 * 65536 + t * 4);
    f32x4 a0 = *(const f32x4*)(ap + t * 4);
    f32x4 a1 = *(const f32x4*)(ap + (512 + t) * 4);
    *(bf16x4*)(lds + XBYT(0)) = CVT4(v0);
    *(bf16x4*)(lds + XBYT(1)) = CVT4(v1);
    *(bf16x4*)(lds + XBYT(2)) = CVT4(v2);
    *(bf16x4*)(lds + XBYT(3)) = CVT4(v3);
    *(bf16x4*)(lds + XBYT(4)) = CVT4(v4);
    *(bf16x4*)(lds + XBYT(5)) = CVT4(v5);
    *(bf16x4*)(lds + XBYT(6)) = CVT4(v6);
    *(bf16x4*)(lds + XBYT(7)) = CVT4(v7);
    AWR(a0, a1);
  }
  asm volatile("s_waitcnt lgkmcnt(0)" ::: "memory");
  __builtin_amdgcn_s_barrier();
  __builtin_amdgcn_sched_barrier(0);

#pragma unroll 1
  for (int i = 0; i < 8; ++i) {
    const int w = w0 + i;
    const char* xs = lds + (i & 1) * 32768;

    // ---- loop-top: issue next window's 10 loads (oldest VMEM ops) ----
    f32x4 px0, px1, px2, px3, px4, px5, px6, px7, pa0, pa1;
    if (i < 7) {
      const float* xp = x + wbase(w + 1);
      const float* ap = attn + (long)(w + 1) * 4096;
      px0 = *(const f32x4*)(xp + 0 * 65536 + t * 4);
      px1 = *(const f32x4*)(xp + 1 * 65536 + t * 4);
      px2 = *(const f32x4*)(xp + 2 * 65536 + t * 4);
      px3 = *(const f32x4*)(xp + 3 * 65536 + t * 4);
      px4 = *(const f32x4*)(xp + 4 * 65536 + t * 4);
      px5 = *(const f32x4*)(xp + 5 * 65536 + t * 4);
      px6 = *(const f32x4*)(xp + 6 * 65536 + t * 4);
      px7 = *(const f32x4*)(xp + 7 * 65536 + t * 4);
      pa0 = *(const f32x4*)(ap + t * 4);
      pa1 = *(const f32x4*)(ap + (512 + t) * 4);
    }
    __builtin_amdgcn_sched_barrier(0);   // pin: loads issued before GEMM1

    // ---- GEMM1: z = xw @ W, K=256. ONE ds_read_b128 per frag, zero cvt ----
    f32x16 acc0 = {}, acc1 = {};
#pragma unroll
    for (int ks = 0; ks < 16; ++ks) {
      int kk = ks * 16 + 8 * lh;
      int byt0 = ln31 * 512 + ((kk * 2) ^ (ln31 << 4));
      bf16x8 a0 = *(const bf16x8*)(xs + byt0);            // toks 0..31
      bf16x8 a1 = *(const bf16x8*)(xs + byt0 + 16384);    // toks 32..63
      acc0 = MFMA32(a0, wb[ks], acc0);
      acc1 = MFMA32(a1, wb[ks], acc1);
    }

    // ---- GEMM2 B-frags in-register ----
    bf16x8 bfr[4];
    build_bfrags(acc0, lh, &bfr[0]);
    build_bfrags(acc1, lh, &bfr[2]);

    float* op = out + wbase(w);
    const int ch = wvi * 32 + ln31;

    // ---- GEMM2 + store, split o0/o1 to cap register pressure ----
    {
      f32x16 o0 = {};
#pragma unroll
      for (int ks = 0; ks < 4; ++ks) {
        int kk = ks * 16 + 8 * lh;
        int ab0 = ln31 * 128 + ((kk * 2) ^ ((ln31 & 7) << 4));
        bf16x8 a0 = *(const bf16x8*)(lds_at + ab0);
        o0 = MFMA32(a0, bfr[ks], o0);
      }
#pragma unroll
      for (int r = 0; r < 16; ++r) {
        int tok = (r & 3) + 8 * (r >> 2) + 4 * lh;
        op[(tok >> 3) * 65536 + (tok & 7) * 256 + ch] = o0[r] + bv;
      }
    }
    {
      f32x16 o1 = {};
#pragma unroll
      for (int ks = 0; ks < 4; ++ks) {
        int kk = ks * 16 + 8 * lh;
        int ab0 = ln31 * 128 + ((kk * 2) ^ ((ln31 & 7) << 4));
        bf16x8 a1 = *(const bf16x8*)(lds_at + ab0 + 4096);
        o1 = MFMA32(a1, bfr[ks], o1);
      }
#pragma unroll
      for (int r = 0; r < 16; ++r) {
        int tok = 32 + (r & 3) + 8 * (r >> 2) + 4 * lh;
        op[(tok >> 3) * 65536 + (tok & 7) * 256 + ch] = o1[r] + bv;
      }
    }

    // ---- mid barrier: all waves done reading attn(w) (single buffer) ----
    asm volatile("s_waitcnt lgkmcnt(0)" ::: "memory");
    __builtin_amdgcn_s_barrier();
    __builtin_amdgcn_sched_barrier(0);

    // ---- staging writes: compiler's wait for the (old) loads is counted
    // (32 newer stores ride). x -> other dbuf half, attn -> single buf. ----
    if (i < 7) {
      char* bxw = lds + ((i + 1) & 1) * 32768;
      *(bf16x4*)(bxw + XBYT(0)) = CVT4(px0);
      *(bf16x4*)(bxw + XBYT(1)) = CVT4(px1);
      *(bf16x4*)(bxw + XBYT(2)) = CVT4(px2);
      *(bf16x4*)(bxw + XBYT(3)) = CVT4(px3);
      *(bf16x4*)(bxw + XBYT(4)) = CVT4(px4);
      *(bf16x4*)(bxw + XBYT(5)) = CVT4(px5);
      *(bf16x4*)(bxw + XBYT(6)) = CVT4(px6);
      *(bf16x4*)(bxw + XBYT(7)) = CVT4(px7);
      AWR(pa0, pa1);
    }

    // ---- end barrier: LDS visibility only; stores ride to kernel end ----
    asm volatile("s_waitcnt lgkmcnt(0)" ::: "memory");
    __builtin_amdgcn_s_barrier();
    __builtin_amdgcn_sched_barrier(0);
  }
#undef XBYT
#undef CVT4
#undef AWR
}

extern "C" void kernel_launch(void* const* d_in, const int* in_sizes, int n_in,
                              void* d_out, int out_size, void* d_ws, size_t ws_size,
                              hipStream_t stream) {
  const float* x    = (const float*)d_in[0];
  const float* attn = (const float*)d_in[1];
  const float* Wv   = (const float*)d_in[2];
  const float* Wo   = (const float*)d_in[3];
  const float* bo   = (const float*)d_in[4];
  float* out = (float*)d_out;
  __bf16* WT = (__bf16*)d_ws;   // 256*256*2 = 128 KB scratch

  wfuse_kernel<<<256, 256, 0, stream>>>(Wv, Wo, WT);
  na_msa_kernel<<<512, 512, 0, stream>>>(x, attn, WT, bo, out);
}